// Round 7
// baseline (286.633 us; speedup 1.0000x reference)
//
#include <hip/hip_runtime.h>

#define BATCH 131072
#define ITERS 2   // element-groups per block; grid = BATCH*4/256/ITERS

typedef float v2f __attribute__((ext_vector_type(2)));

__device__ __forceinline__ float fast_tanh(float v) {
    float e = __expf(2.0f * v);
    return 1.0f - 2.0f / (e + 1.0f);
}

template <int CTRL>
__device__ __forceinline__ float dppf(float v) {
    return __int_as_float(__builtin_amdgcn_update_dpp(
        0, __float_as_int(v), CTRL, 0xF, 0xF, true));
}
#define DPP_XOR1 0xB1  // quad_perm [1,0,3,2]
#define DPP_XOR2 0x4E  // quad_perm [2,3,0,1]

__device__ __forceinline__ v2f swap2(v2f v) { return __builtin_shufflevector(v, v, 1, 0); }

// ---------------------------------------------------------------------------
// Packed butterflies. State: v2f packs P[j] = (amp(m=2j), amp(m=2j+1)),
// amplitude r = 4m + sub, sub = lane&3.
// ---------------------------------------------------------------------------
template <int MASK>  // pack-to-pack RX (wires 0..2: j bits 2,1,0)
__device__ __forceinline__ void rx_pairs(v2f* zr, v2f* zi, float c, float s) {
#pragma unroll
    for (int j = 0; j < 8; ++j) {
        if (j & MASK) continue;
        int j1 = j | MASK;
        v2f ar = zr[j], ai = zi[j], br = zr[j1], bi = zi[j1];
        zr[j]  = c * ar + s * bi;
        zi[j]  = c * ai - s * br;
        zr[j1] = c * br + s * ai;
        zi[j1] = c * bi - s * ar;
    }
}

template <int CTRL>  // cross-lane RX (wires 4,5: lane bits)
__device__ __forceinline__ void rx_exch2(v2f* zr, v2f* zi, float c, float s) {
#pragma unroll
    for (int j = 0; j < 8; ++j) {
        v2f pr, pi;
        pr.x = dppf<CTRL>(zr[j].x);
        pr.y = dppf<CTRL>(zr[j].y);
        pi.x = dppf<CTRL>(zi[j].x);
        pi.y = dppf<CTRL>(zi[j].y);
        v2f mr = zr[j], mi = zi[j];
        zr[j] = c * mr + s * pi;
        zi[j] = c * mi - s * pr;
    }
}

// wires 1..5 + diagonal of one block (wire 0 handled by caller)
__device__ __forceinline__ void enc_tail(v2f* zr, v2f* zi, const float* rx,
                                         const float* sDblk, int sub) {
    rx_pairs<2>(zr, zi, rx[2], rx[3]);     // wire 1: r bit4 = j bit1
    rx_pairs<1>(zr, zi, rx[4], rx[5]);     // wire 2: r bit3 = j bit0
    {                                       // wire 3: r bit2 = pack half
        float c = rx[6], s = rx[7];
#pragma unroll
        for (int j = 0; j < 8; ++j) {
            v2f orr = zr[j], oi = zi[j];
            zr[j] = c * orr + s * swap2(oi);
            zi[j] = c * oi - s * swap2(orr);
        }
    }
    rx_exch2<DPP_XOR2>(zr, zi, rx[8], rx[9]);    // wire 4: lane bit1
    rx_exch2<DPP_XOR1>(zr, zi, rx[10], rx[11]);  // wire 5: lane bit0
#pragma unroll
    for (int j = 0; j < 8; ++j) {
        float4 d = *(const float4*)&sDblk[(j * 4 + sub) * 4];
        v2f dr = {d.x, d.y}, di = {d.z, d.w};
        v2f orr = zr[j], oi = zi[j];
        zr[j] = dr * orr - di * oi;
        zi[j] = dr * oi + di * orr;
    }
}

// ---------------------------------------------------------------------------
// one 64-element group: load x -> h-matmul -> encoder -> latent -> folded
// decoder -> out. x is loaded HERE from a runtime address (address math is
// safe; runtime-indexed register arrays are not — rule #20 / round-5 bug).
// Exactly ONE copy of this body exists in the kernel (round-6 bug was two
// inlined copies interleaving -> register blowup -> scratch spill).
// ---------------------------------------------------------------------------
__device__ __forceinline__ void process_group(size_t b, const float* __restrict__ x,
                                              const float* sW, const float* sB,
                                              const float* sD, const float* sRx,
                                              int sub, float* __restrict__ out) {
    const float* xp = x + b * 6;
    float2 xA = *(const float2*)(xp);
    float2 xB = *(const float2*)(xp + 2);
    float2 xC = *(const float2*)(xp + 4);
    float xv[6] = {xA.x, xA.y, xB.x, xB.y, xC.x, xC.y};

    // h = tanh(xW^T+b): pack j holds rows (8j+sub, 8j+4+sub). zi starts 0.
    v2f zr[8], zi[8];
    v2f S2 = {0.0f, 0.0f};
#pragma unroll
    for (int j = 0; j < 8; ++j) {
        const float* wb = &sW[(j * 4 + sub) * 16 + j * 4];
        float4 c0 = *(const float4*)wb;
        float4 c1 = *(const float4*)(wb + 4);
        float4 c2 = *(const float4*)(wb + 8);
        float4 c3 = *(const float4*)(wb + 12);
        v2f a = {c3.x, c3.y};
        a += xv[0] * (v2f){c0.x, c0.y};
        a += xv[1] * (v2f){c0.z, c0.w};
        a += xv[2] * (v2f){c1.x, c1.y};
        a += xv[3] * (v2f){c1.z, c1.w};
        a += xv[4] * (v2f){c2.x, c2.y};
        a += xv[5] * (v2f){c2.z, c2.w};
        v2f th = {fast_tanh(a.x), fast_tanh(a.y)};
        zr[j] = th;
        S2 += th * th;
    }
    float S = S2.x + S2.y;
    S += dppf<DPP_XOR1>(S);
    S += dppf<DPP_XOR2>(S);
    float invS = __builtin_amdgcn_rcpf(S);

    // ---- block 0: wire 0 specialized for real input (zi==0) ----
    {
        const float* rx = sRx;
        float c = rx[0], s = rx[1];
#pragma unroll
        for (int j = 0; j < 4; ++j) {
            v2f a = zr[j], b2 = zr[j + 4];
            zr[j]     = c * a;
            zi[j]     = -s * b2;
            zr[j + 4] = c * b2;
            zi[j + 4] = -s * a;
        }
        enc_tail(zr, zi, rx, sD, sub);
    }
    // ---- block 1: generic ----
    {
        const float* rx = sRx + 12;
        rx_pairs<4>(zr, zi, rx[0], rx[1]);
        enc_tail(zr, zi, rx, sD + 128, sub);
    }

    // latent via folded block-2 observable:
    //   latent_k = (cos(tx_k)*<Z_k> + sin(tx_k)*<Y_k>)/S
    v2f L0 = {0, 0}, L1 = {0, 0}, L2 = {0, 0};
#pragma unroll
    for (int j = 0; j < 8; ++j) {
        v2f p = zr[j] * zr[j] + zi[j] * zi[j];
        L0 += (j & 4) ? -p : p;
        L1 += (j & 2) ? -p : p;
        L2 += (j & 1) ? -p : p;
    }
    v2f Y0 = {0, 0}, Y1 = {0, 0}, Y2 = {0, 0};
#pragma unroll
    for (int j = 0; j < 4; ++j)
        Y0 += zr[j] * zi[j | 4] - zi[j] * zr[j | 4];
#pragma unroll
    for (int j0 = 0; j0 < 8; j0 += 4)
#pragma unroll
        for (int j = j0; j < j0 + 2; ++j)
            Y1 += zr[j] * zi[j | 2] - zi[j] * zr[j | 2];
#pragma unroll
    for (int j = 0; j < 8; j += 2)
        Y2 += zr[j] * zi[j | 1] - zi[j] * zr[j | 1];

    // combine with block-2 coeffs BEFORE cross-lane reduce: 6 DPP not 12
    const float* p2 = sRx + 24;
    float t0 = p2[0] * (L0.x + L0.y) + p2[1] * (Y0.x + Y0.y);
    float t1 = p2[2] * (L1.x + L1.y) + p2[3] * (Y1.x + Y1.y);
    float t2 = p2[4] * (L2.x + L2.y) + p2[5] * (Y2.x + Y2.y);
    t0 += dppf<DPP_XOR1>(t0); t0 += dppf<DPP_XOR2>(t0);
    t1 += dppf<DPP_XOR1>(t1); t1 += dppf<DPP_XOR2>(t1);
    t2 += dppf<DPP_XOR1>(t2); t2 += dppf<DPP_XOR2>(t2);
    float l0 = t0 * invS, l1 = t1 * invS, l2 = t2 * invS;

    // latent out (direct, no LDS round-trip / no barrier)
    if (sub == 0) {
        size_t lo = (size_t)BATCH * 64 + b * 3;
        out[lo]     = l0;
        out[lo + 1] = l1;
        out[lo + 2] = l2;
    }

    // q-hat = q * inv(l^T l); pre_row = B[row]·q-hat + bias_row
    float q0 = l0 * l0, q1 = l1 * l1, q2 = l2 * l2;
    float invr2 = __builtin_amdgcn_rcpf(q0 + q1 + q2);
    float qh0 = q0 * invr2, qh1 = q1 * invr2, qh2 = q2 * invr2;
    float qh3 = (l0 * l1) * invr2, qh4 = (l0 * l2) * invr2, qh5 = (l1 * l2) * invr2;

    // reconstructed = tanh(B q-hat + b); thread covers rows 16*sub..16*sub+15
    const float* bB = &sB[132 * sub];   // 132 = 16*8 + 4 (swizzled row base)
    const size_t ob = b * 64 + 16 * sub;
#pragma unroll
    for (int ch = 0; ch < 4; ++ch) {
        float v4[4];
#pragma unroll
        for (int r = 0; r < 4; ++r) {
            int qq = ch * 4 + r;
            float4 u0 = *(const float4*)&bB[8 * qq];
            float4 u1 = *(const float4*)&bB[8 * qq + 4];  // B4,B5,bias,pad
            float acc = u1.z
                      + qh0 * u0.x + qh1 * u0.y + qh2 * u0.z + qh3 * u0.w
                      + qh4 * u1.x + qh5 * u1.y;
            v4[r] = fast_tanh(acc);
        }
        float4 o = {v4[0], v4[1], v4[2], v4[3]};
        *(float4*)&out[ob + ch * 4] = o;
    }
}

// ---------------------------------------------------------------------------
// Fully fused kernel, ITERS groups/block via a genuine (non-unrolled) loop:
// prep params once in LDS, then process ITERS groups of 64 batch elements.
//
// Prep butterfly evolves ONLY columns 0..2 of the decoder unitary (cols 3..7
// are identically zero). Layout Sr/Si[64][4]; threads t<128 active in the
// butterfly.
//
// LDS phase plan (shbuf aliased; barrier-separated):
//   phase A (prep):  gt[144] @0 | Sr[256] @144 | Si[256] @400
//   phase B (main):  sW[544] @0 | sB[544] @544 | sD[256] @1088
//   persistent:      sA[36], sRx[36]
// ---------------------------------------------------------------------------
__global__ __launch_bounds__(256, 4) void qae_fused(const float* __restrict__ x,
                                                    const float* __restrict__ Wp,
                                                    const float* __restrict__ bp,
                                                    const float* __restrict__ enc_w,
                                                    const float* __restrict__ dec_w,
                                                    float* __restrict__ out) {
    __shared__ __align__(16) float shbuf[1344];
    __shared__ float sA[36];
    __shared__ float sRx[36];

    float* gt = shbuf;          // [18][8]
    float* Sr = shbuf + 144;    // [64][4]
    float* Si = shbuf + 400;    // [64][4]
    float* sW = shbuf;          // [544] phase B
    float* sB = shbuf + 544;    // [544]
    float* sD = shbuf + 1088;   // [256]

    const int t = threadIdx.x;
    const int bl = t >> 2;
    const int sub = t & 3;
    const size_t b0 = (size_t)blockIdx.x * (64 * ITERS) + bl;

    // ---------------- phase A: decoder butterfly prep (cols 0..2) ----------
    if (t < 18) {
        float tx = dec_w[t * 3 + 0];
        float tz = dec_w[t * 3 + 1];
        float c = cosf(0.5f * tx), s = sinf(0.5f * tx);
        float ch = cosf(0.5f * tz), sh = sinf(0.5f * tz);
        gt[t * 8 + 0] = c * ch;  gt[t * 8 + 1] = -c * sh;
        gt[t * 8 + 2] = -s * sh; gt[t * 8 + 3] = -s * ch;
        gt[t * 8 + 4] = s * sh;  gt[t * 8 + 5] = -s * ch;
        gt[t * 8 + 6] = c * ch;  gt[t * 8 + 7] = c * sh;
        // enc RX coeffs (independent)
        float etx = enc_w[t * 3 + 0];
        float ec = cosf(0.5f * etx), es = sinf(0.5f * etx);
        if (t >= 12) {  // block 2 folded into observable
            sRx[2 * t] = ec * ec - es * es;   // cos(tx)
            sRx[2 * t + 1] = 4.0f * ec * es;  // 2*sin(tx)
        } else {
            sRx[2 * t] = ec;
            sRx[2 * t + 1] = es;
        }
    }
    {   // init: 64 rows x 4 cols (col 3 dead-zero, branch-free)
        int r = t >> 2, c = t & 3;
        Sr[t] = (r == c && c < 3) ? 1.0f : 0.0f;
        Si[t] = 0.0f;
    }

    const int cl = t & 3;
    const int pr = t >> 2;   // 0..31 for t<128 (row-pair index)
    for (int bb = 0; bb < 3; ++bb) {
        for (int w = 0; w < 6; ++w) {
            __syncthreads();
            if (t < 128) {
                int g = bb * 6 + w;
                int p = 5 - w;
                float u00r = gt[g * 8 + 0], u00i = gt[g * 8 + 1], u01r = gt[g * 8 + 2], u01i = gt[g * 8 + 3];
                float u10r = gt[g * 8 + 4], u10i = gt[g * 8 + 5], u11r = gt[g * 8 + 6], u11i = gt[g * 8 + 7];
                int r0 = ((pr >> p) << (p + 1)) | (pr & ((1 << p) - 1));
                int r1 = r0 | (1 << p);
                float ar = Sr[r0 * 4 + cl], ai = Si[r0 * 4 + cl];
                float br = Sr[r1 * 4 + cl], bi = Si[r1 * 4 + cl];
                Sr[r0 * 4 + cl] = u00r * ar - u00i * ai + u01r * br - u01i * bi;
                Si[r0 * 4 + cl] = u00r * ai + u00i * ar + u01r * bi + u01i * br;
                Sr[r1 * 4 + cl] = u10r * ar - u10i * ai + u11r * br - u11i * bi;
                Si[r1 * 4 + cl] = u10r * ai + u10i * ar + u11r * bi + u11i * br;
            }
        }
        __syncthreads();
        {   // CZ sign fold (all 256 threads, one elem each)
            int r = t >> 2;
            if (__popc(r & (r >> 1)) & 1) {
                Sr[t] = -Sr[t];
                Si[t] = -Si[t];
            }
        }
    }
    __syncthreads();

    // folded decoder quadratic forms A' (6 coeffs per output k)
    if (t < 36) {
        int k = t / 6, i = t % 6;
        int d = (i < 3) ? i : ((i == 5) ? 1 : 0);  // i=3->(0,1) i=4->(0,2) i=5->(1,2)
        int e = (i < 3) ? i : ((i == 3) ? 1 : 2);
        float acc = 0.0f;
        for (int r = 0; r < 64; ++r) {
            float term = Sr[r * 4 + d] * Sr[r * 4 + e] + Si[r * 4 + d] * Si[r * 4 + e];
            acc += ((r >> (5 - k)) & 1) ? -term : term;
        }
        if (i >= 3) acc *= 2.0f;  // symmetric off-diagonal folded
        sA[t] = acc;
    }
    __syncthreads();   // sA ready; Sr/Si/gt dead -> phase B may overwrite

    // ---------------- phase B: stage main LDS ----------------
    // sW: group g = j*4+su holds rows (8j+su, 8j+4+su) interleaved:
    //   phys(g,e) = g*16 + (g>>2)*4 + e ; e = 2d+half for W, 12+half bias, 14 pad
    for (int f = t; f < 512; f += 256) {
        int g = f >> 4, e = f & 15;
        int j = g >> 2, su = g & 3;
        float val;
        if (e < 12)      { int row = 8 * j + su + 4 * (e & 1); val = Wp[row * 6 + (e >> 1)]; }
        else if (e < 14) { int row = 8 * j + su + 4 * (e - 12); val = bp[row]; }
        else val = 0.0f;
        sW[g * 16 + j * 4 + e] = val;
    }
    // sB: B[row] = W[row,:]·A' (decoder + output matmul collapsed), swizzled
    //   row r at phys r*8 + (r>>4)*4 -> conflict-free b128 reads per sub group
    if (t < 64) {
        float w0 = Wp[t * 6 + 0], w1 = Wp[t * 6 + 1], w2 = Wp[t * 6 + 2];
        float w3 = Wp[t * 6 + 3], w4 = Wp[t * 6 + 4], w5 = Wp[t * 6 + 5];
        int basep = 8 * t + ((t >> 4) << 2);
#pragma unroll
        for (int i = 0; i < 6; ++i) {
            float acc = w0 * sA[0 * 6 + i] + w1 * sA[1 * 6 + i] + w2 * sA[2 * 6 + i]
                      + w3 * sA[3 * 6 + i] + w4 * sA[4 * 6 + i] + w5 * sA[5 * 6 + i];
            sB[basep + i] = acc;
        }
        sB[basep + 6] = bp[t];
        sB[basep + 7] = 0.0f;
    }
    // sD: enc diag (blocks 0,1), layout ((bb*8+j)*4+su)*4 = (DrLo,DrHi,DiLo,DiHi)
    if (t >= 64 && t < 192) {
        int idx = t - 64;
        int bb = idx >> 6, r = idx & 63;
        float phi = 0.0f;
        for (int k = 0; k < 6; ++k) {
            float tz = enc_w[(bb * 6 + k) * 3 + 1];
            phi += ((r >> (5 - k)) & 1) ? 0.5f * tz : -0.5f * tz;
        }
        float sgn = (__popc(r & (r >> 1)) & 1) ? -1.0f : 1.0f;
        int su = r & 3, m = r >> 2, j = m >> 1, hm = m & 1;
        int base = ((bb * 8 + j) * 4 + su) * 4;
        sD[base + hm]     = sgn * cosf(phi);
        sD[base + 2 + hm] = sgn * sinf(phi);
    }
    __syncthreads();

    // ---------------- main compute: ITERS groups, ONE body ----------------
#pragma unroll 1
    for (int it = 0; it < ITERS; ++it) {
        process_group(b0 + (size_t)it * 64, x, sW, sB, sD, sRx, sub, out);
    }
}

extern "C" void kernel_launch(void* const* d_in, const int* in_sizes, int n_in,
                              void* d_out, int out_size, void* d_ws, size_t ws_size,
                              hipStream_t stream) {
    const float* x   = (const float*)d_in[0];
    const float* Wp  = (const float*)d_in[1];
    const float* bpv = (const float*)d_in[2];
    const float* enc = (const float*)d_in[3];
    const float* dec = (const float*)d_in[4];
    float* out = (float*)d_out;

    qae_fused<<<(BATCH * 4) / 256 / ITERS, 256, 0, stream>>>(x, Wp, bpv, enc, dec, out);
}

// Round 8
// 100.256 us; speedup vs baseline: 2.8590x; 2.8590x over previous
//
#include <hip/hip_runtime.h>

#define BATCH 131072

typedef float v2f __attribute__((ext_vector_type(2)));

__device__ __forceinline__ float fast_tanh(float v) {
    float e = __expf(2.0f * v);
    return 1.0f - 2.0f / (e + 1.0f);
}

template <int CTRL>
__device__ __forceinline__ float dppf(float v) {
    return __int_as_float(__builtin_amdgcn_update_dpp(
        0, __float_as_int(v), CTRL, 0xF, 0xF, true));
}
#define DPP_XOR1 0xB1  // quad_perm [1,0,3,2]
#define DPP_XOR2 0x4E  // quad_perm [2,3,0,1]

__device__ __forceinline__ v2f swap2(v2f v) { return __builtin_shufflevector(v, v, 1, 0); }

// ---------------------------------------------------------------------------
// Packed butterflies. State: v2f packs P[j] = (amp(m=2j), amp(m=2j+1)),
// amplitude r = 4m + sub, sub = lane&3.
// ---------------------------------------------------------------------------
template <int MASK>  // pack-to-pack RX (wires 0..2: j bits 2,1,0)
__device__ __forceinline__ void rx_pairs(v2f* zr, v2f* zi, float c, float s) {
#pragma unroll
    for (int j = 0; j < 8; ++j) {
        if (j & MASK) continue;
        int j1 = j | MASK;
        v2f ar = zr[j], ai = zi[j], br = zr[j1], bi = zi[j1];
        zr[j]  = c * ar + s * bi;
        zi[j]  = c * ai - s * br;
        zr[j1] = c * br + s * ai;
        zi[j1] = c * bi - s * ar;
    }
}

template <int CTRL>  // cross-lane RX (wires 4,5: lane bits)
__device__ __forceinline__ void rx_exch2(v2f* zr, v2f* zi, float c, float s) {
#pragma unroll
    for (int j = 0; j < 8; ++j) {
        v2f pr, pi;
        pr.x = dppf<CTRL>(zr[j].x);
        pr.y = dppf<CTRL>(zr[j].y);
        pi.x = dppf<CTRL>(zi[j].x);
        pi.y = dppf<CTRL>(zi[j].y);
        v2f mr = zr[j], mi = zi[j];
        zr[j] = c * mr + s * pi;
        zi[j] = c * mi - s * pr;
    }
}

// wires 1..5 + diagonal of one block (wire 0 handled by caller)
__device__ __forceinline__ void enc_tail(v2f* zr, v2f* zi, const float* rx,
                                         const float* sDblk, int sub) {
    rx_pairs<2>(zr, zi, rx[2], rx[3]);     // wire 1: r bit4 = j bit1
    rx_pairs<1>(zr, zi, rx[4], rx[5]);     // wire 2: r bit3 = j bit0
    {                                       // wire 3: r bit2 = pack half
        float c = rx[6], s = rx[7];
#pragma unroll
        for (int j = 0; j < 8; ++j) {
            v2f orr = zr[j], oi = zi[j];
            zr[j] = c * orr + s * swap2(oi);
            zi[j] = c * oi - s * swap2(orr);
        }
    }
    rx_exch2<DPP_XOR2>(zr, zi, rx[8], rx[9]);    // wire 4: lane bit1
    rx_exch2<DPP_XOR1>(zr, zi, rx[10], rx[11]);  // wire 5: lane bit0
#pragma unroll
    for (int j = 0; j < 8; ++j) {
        float4 d = *(const float4*)&sDblk[(j * 4 + sub) * 4];
        v2f dr = {d.x, d.y}, di = {d.z, d.w};
        v2f orr = zr[j], oi = zi[j];
        zr[j] = dr * orr - di * oi;
        zi[j] = dr * oi + di * orr;
    }
}

// ---------------------------------------------------------------------------
// Fused kernel, ONE group per block (multi-group packaging proven toxic:
// R5/R6/R7 all scratch-spilled). Prep is wave-specialized instead:
//   wave 0 : decoder butterfly (3-col layout), BARRIER-FREE in-wave lockstep
//   waves 1-2 : stage sW
//   wave 3 : sD diagonal trig
// then 3 barriers total (staging / sA / sB). Main body verbatim R4 (44.5us).
// LDS is NOT aliased (8.3 KB) so the phases can overlap across waves.
// ---------------------------------------------------------------------------
__global__ __launch_bounds__(256, 4) void qae_fused(const float* __restrict__ x,
                                                    const float* __restrict__ Wp,
                                                    const float* __restrict__ bp,
                                                    const float* __restrict__ enc_w,
                                                    const float* __restrict__ dec_w,
                                                    float* __restrict__ out) {
    __shared__ __align__(16) float gt[144];   // 18 gates x 8
    __shared__ __align__(16) float Sr[256];   // [64][4], cols 0..2 live
    __shared__ __align__(16) float Si[256];
    __shared__ float sA[36];
    __shared__ float sRx[36];
    __shared__ __align__(16) float sW[544];
    __shared__ __align__(16) float sB[544];
    __shared__ __align__(16) float sD[256];

    const int t = threadIdx.x;
    const int bl = t >> 2;
    const int sub = t & 3;

    // hoist x load: latency hides under prep
    const size_t b = (size_t)blockIdx.x * 64 + bl;
    const float* xp = x + b * 6;
    float2 x01 = *(const float2*)(xp);
    float2 x23 = *(const float2*)(xp + 2);
    float2 x45 = *(const float2*)(xp + 4);

    if (t < 64) {
        // ================= wave 0: butterfly prep, no barriers =============
        if (t < 18) {
            float tx = dec_w[t * 3 + 0];
            float tz = dec_w[t * 3 + 1];
            float c = cosf(0.5f * tx), s = sinf(0.5f * tx);
            float ch = cosf(0.5f * tz), sh = sinf(0.5f * tz);
            gt[t * 8 + 0] = c * ch;  gt[t * 8 + 1] = -c * sh;
            gt[t * 8 + 2] = -s * sh; gt[t * 8 + 3] = -s * ch;
            gt[t * 8 + 4] = s * sh;  gt[t * 8 + 5] = -s * ch;
            gt[t * 8 + 6] = c * ch;  gt[t * 8 + 7] = c * sh;
            // enc RX coeffs
            float etx = enc_w[t * 3 + 0];
            float ec = cosf(0.5f * etx), es = sinf(0.5f * etx);
            if (t >= 12) {  // block 2 folded into observable
                sRx[2 * t] = ec * ec - es * es;   // cos(tx)
                sRx[2 * t + 1] = 4.0f * ec * es;  // 2*sin(tx)
            } else {
                sRx[2 * t] = ec;
                sRx[2 * t + 1] = es;
            }
        }
        // init Sr/Si[64][4] (col 3 dead-zero)
#pragma unroll
        for (int q = 0; q < 4; ++q) {
            int f = t + 64 * q;
            int r = f >> 2, c = f & 3;
            Sr[f] = (r == c && c < 3) ? 1.0f : 0.0f;
            Si[f] = 0.0f;
        }
        const int cl = t & 3;
        const int pq = t >> 2;   // 0..15
        for (int bb = 0; bb < 3; ++bb) {
            for (int w = 0; w < 6; ++w) {
                int g = bb * 6 + w;
                int p = 5 - w;
                float u00r = gt[g * 8 + 0], u00i = gt[g * 8 + 1];
                float u01r = gt[g * 8 + 2], u01i = gt[g * 8 + 3];
                float u10r = gt[g * 8 + 4], u10i = gt[g * 8 + 5];
                float u11r = gt[g * 8 + 6], u11i = gt[g * 8 + 7];
#pragma unroll
                for (int h = 0; h < 2; ++h) {
                    int pp = pq + 16 * h;
                    int r0 = ((pp >> p) << (p + 1)) | (pp & ((1 << p) - 1));
                    int r1 = r0 | (1 << p);
                    float ar = Sr[r0 * 4 + cl], ai = Si[r0 * 4 + cl];
                    float br = Sr[r1 * 4 + cl], bi = Si[r1 * 4 + cl];
                    Sr[r0 * 4 + cl] = u00r * ar - u00i * ai + u01r * br - u01i * bi;
                    Si[r0 * 4 + cl] = u00r * ai + u00i * ar + u01r * bi + u01i * br;
                    Sr[r1 * 4 + cl] = u10r * ar - u10i * ai + u11r * br - u11i * bi;
                    Si[r1 * 4 + cl] = u10r * ai + u10i * ar + u11r * bi + u11i * br;
                }
            }
            // CZ sign fold (in-wave)
#pragma unroll
            for (int q = 0; q < 4; ++q) {
                int f = t + 64 * q;
                int r = f >> 2;
                if (__popc(r & (r >> 1)) & 1) {
                    Sr[f] = -Sr[f];
                    Si[f] = -Si[f];
                }
            }
        }
    } else if (t < 192) {
        // ================= waves 1-2: stage sW ============================
        // group g = j*4+su holds rows (8j+su, 8j+4+su) interleaved:
        //   phys(g,e) = g*16 + (g>>2)*4 + e; e=2d+half W, 12+half bias, 14 pad
#pragma unroll
        for (int q = 0; q < 4; ++q) {
            int f = (t - 64) + 128 * q;
            int g = f >> 4, e = f & 15;
            int j = g >> 2, su = g & 3;
            float val;
            if (e < 12)      { int row = 8 * j + su + 4 * (e & 1); val = Wp[row * 6 + (e >> 1)]; }
            else if (e < 14) { int row = 8 * j + su + 4 * (e - 12); val = bp[row]; }
            else val = 0.0f;
            sW[g * 16 + j * 4 + e] = val;
        }
    } else {
        // ================= wave 3: sD enc diag trig =======================
        // layout ((bb*8+j)*4+su)*4 = (DrLo,DrHi,DiLo,DiHi)
#pragma unroll
        for (int q = 0; q < 2; ++q) {
            int idx = (t - 192) + 64 * q;
            int bb = idx >> 6, r = idx & 63;
            float phi = 0.0f;
            for (int k = 0; k < 6; ++k) {
                float tz = enc_w[(bb * 6 + k) * 3 + 1];
                phi += ((r >> (5 - k)) & 1) ? 0.5f * tz : -0.5f * tz;
            }
            float sgn = (__popc(r & (r >> 1)) & 1) ? -1.0f : 1.0f;
            int su = r & 3, m = r >> 2, j = m >> 1, hm = m & 1;
            int base = ((bb * 8 + j) * 4 + su) * 4;
            sD[base + hm]     = sgn * cosf(phi);
            sD[base + 2 + hm] = sgn * sinf(phi);
        }
    }
    __syncthreads();

    // folded decoder quadratic forms A' (6 coeffs per output k)
    if (t < 36) {
        int k = t / 6, i = t % 6;
        int d = (i < 3) ? i : ((i == 5) ? 1 : 0);  // i=3->(0,1) i=4->(0,2) i=5->(1,2)
        int e = (i < 3) ? i : ((i == 3) ? 1 : 2);
        float acc = 0.0f;
        for (int r = 0; r < 64; ++r) {
            float term = Sr[r * 4 + d] * Sr[r * 4 + e] + Si[r * 4 + d] * Si[r * 4 + e];
            acc += ((r >> (5 - k)) & 1) ? -term : term;
        }
        if (i >= 3) acc *= 2.0f;  // symmetric off-diagonal folded
        sA[t] = acc;
    }
    __syncthreads();

    // sB: B[row] = W[row,:]·A' (decoder + output matmul collapsed), swizzled
    //   row r at phys r*8 + (r>>4)*4 -> conflict-free b128 reads per sub group
    if (t < 64) {
        float w0 = Wp[t * 6 + 0], w1 = Wp[t * 6 + 1], w2 = Wp[t * 6 + 2];
        float w3 = Wp[t * 6 + 3], w4 = Wp[t * 6 + 4], w5 = Wp[t * 6 + 5];
        int basep = 8 * t + ((t >> 4) << 2);
#pragma unroll
        for (int i = 0; i < 6; ++i) {
            float acc = w0 * sA[0 * 6 + i] + w1 * sA[1 * 6 + i] + w2 * sA[2 * 6 + i]
                      + w3 * sA[3 * 6 + i] + w4 * sA[4 * 6 + i] + w5 * sA[5 * 6 + i];
            sB[basep + i] = acc;
        }
        sB[basep + 6] = bp[t];
        sB[basep + 7] = 0.0f;
    }
    __syncthreads();

    // ================= main compute (verbatim R4) ==========================
    float xv[6] = {x01.x, x01.y, x23.x, x23.y, x45.x, x45.y};

    // h = tanh(xW^T+b): pack j holds rows (8j+sub, 8j+4+sub). zi starts 0.
    v2f zr[8], zi[8];
    v2f S2 = {0.0f, 0.0f};
#pragma unroll
    for (int j = 0; j < 8; ++j) {
        const float* wb = &sW[(j * 4 + sub) * 16 + j * 4];
        float4 c0 = *(const float4*)wb;
        float4 c1 = *(const float4*)(wb + 4);
        float4 c2 = *(const float4*)(wb + 8);
        float4 c3 = *(const float4*)(wb + 12);
        v2f a = {c3.x, c3.y};
        a += xv[0] * (v2f){c0.x, c0.y};
        a += xv[1] * (v2f){c0.z, c0.w};
        a += xv[2] * (v2f){c1.x, c1.y};
        a += xv[3] * (v2f){c1.z, c1.w};
        a += xv[4] * (v2f){c2.x, c2.y};
        a += xv[5] * (v2f){c2.z, c2.w};
        v2f th = {fast_tanh(a.x), fast_tanh(a.y)};
        zr[j] = th;
        S2 += th * th;
    }
    float S = S2.x + S2.y;
    S += dppf<DPP_XOR1>(S);
    S += dppf<DPP_XOR2>(S);
    float invS = __builtin_amdgcn_rcpf(S);

    // ---- block 0: wire 0 specialized for real input (zi==0) ----
    {
        const float* rx = sRx;
        float c = rx[0], s = rx[1];
#pragma unroll
        for (int j = 0; j < 4; ++j) {
            v2f a = zr[j], b2 = zr[j + 4];
            zr[j]     = c * a;
            zi[j]     = -s * b2;
            zr[j + 4] = c * b2;
            zi[j + 4] = -s * a;
        }
        enc_tail(zr, zi, rx, sD, sub);
    }
    // ---- block 1: generic ----
    {
        const float* rx = sRx + 12;
        rx_pairs<4>(zr, zi, rx[0], rx[1]);
        enc_tail(zr, zi, rx, sD + 128, sub);
    }

    // latent via folded block-2 observable:
    //   latent_k = (cos(tx_k)*<Z_k> + sin(tx_k)*<Y_k>)/S
    v2f L0 = {0, 0}, L1 = {0, 0}, L2 = {0, 0};
#pragma unroll
    for (int j = 0; j < 8; ++j) {
        v2f p = zr[j] * zr[j] + zi[j] * zi[j];
        L0 += (j & 4) ? -p : p;
        L1 += (j & 2) ? -p : p;
        L2 += (j & 1) ? -p : p;
    }
    v2f Y0 = {0, 0}, Y1 = {0, 0}, Y2 = {0, 0};
#pragma unroll
    for (int j = 0; j < 4; ++j)
        Y0 += zr[j] * zi[j | 4] - zi[j] * zr[j | 4];
#pragma unroll
    for (int j0 = 0; j0 < 8; j0 += 4)
#pragma unroll
        for (int j = j0; j < j0 + 2; ++j)
            Y1 += zr[j] * zi[j | 2] - zi[j] * zr[j | 2];
#pragma unroll
    for (int j = 0; j < 8; j += 2)
        Y2 += zr[j] * zi[j | 1] - zi[j] * zr[j | 1];

    // combine with block-2 coeffs BEFORE cross-lane reduce: 6 DPP not 12
    const float* p2 = sRx + 24;
    float t0 = p2[0] * (L0.x + L0.y) + p2[1] * (Y0.x + Y0.y);
    float t1 = p2[2] * (L1.x + L1.y) + p2[3] * (Y1.x + Y1.y);
    float t2 = p2[4] * (L2.x + L2.y) + p2[5] * (Y2.x + Y2.y);
    t0 += dppf<DPP_XOR1>(t0); t0 += dppf<DPP_XOR2>(t0);
    t1 += dppf<DPP_XOR1>(t1); t1 += dppf<DPP_XOR2>(t1);
    t2 += dppf<DPP_XOR1>(t2); t2 += dppf<DPP_XOR2>(t2);
    float l0 = t0 * invS, l1 = t1 * invS, l2 = t2 * invS;

    // latent out (direct, no LDS round-trip / no barrier)
    if (sub == 0) {
        size_t lo = (size_t)BATCH * 64 + b * 3;
        out[lo]     = l0;
        out[lo + 1] = l1;
        out[lo + 2] = l2;
    }

    // q-hat = q * inv(l^T l); pre_row = B[row]·q-hat + bias_row
    float q0 = l0 * l0, q1 = l1 * l1, q2 = l2 * l2;
    float invr2 = __builtin_amdgcn_rcpf(q0 + q1 + q2);
    float qh0 = q0 * invr2, qh1 = q1 * invr2, qh2 = q2 * invr2;
    float qh3 = (l0 * l1) * invr2, qh4 = (l0 * l2) * invr2, qh5 = (l1 * l2) * invr2;

    // reconstructed = tanh(B q-hat + b); thread covers rows 16*sub..16*sub+15
    const float* bB = &sB[132 * sub];   // 132 = 16*8 + 4 (swizzled row base)
    const size_t ob = b * 64 + 16 * sub;
#pragma unroll
    for (int ch = 0; ch < 4; ++ch) {
        float v4[4];
#pragma unroll
        for (int r = 0; r < 4; ++r) {
            int qq = ch * 4 + r;
            float4 u0 = *(const float4*)&bB[8 * qq];
            float4 u1 = *(const float4*)&bB[8 * qq + 4];  // B4,B5,bias,pad
            float acc = u1.z
                      + qh0 * u0.x + qh1 * u0.y + qh2 * u0.z + qh3 * u0.w
                      + qh4 * u1.x + qh5 * u1.y;
            v4[r] = fast_tanh(acc);
        }
        float4 o = {v4[0], v4[1], v4[2], v4[3]};
        *(float4*)&out[ob + ch * 4] = o;
    }
}

extern "C" void kernel_launch(void* const* d_in, const int* in_sizes, int n_in,
                              void* d_out, int out_size, void* d_ws, size_t ws_size,
                              hipStream_t stream) {
    const float* x   = (const float*)d_in[0];
    const float* Wp  = (const float*)d_in[1];
    const float* bpv = (const float*)d_in[2];
    const float* enc = (const float*)d_in[3];
    const float* dec = (const float*)d_in[4];
    float* out = (float*)d_out;

    qae_fused<<<(BATCH * 4) / 256, 256, 0, stream>>>(x, Wp, bpv, enc, dec, out);
}

// Round 9
// 99.327 us; speedup vs baseline: 2.8857x; 1.0094x over previous
//
#include <hip/hip_runtime.h>

#define BATCH 131072

typedef float v2f __attribute__((ext_vector_type(2)));

__device__ __forceinline__ float fast_tanh(float v) {
    float e = __expf(2.0f * v);
    return 1.0f - 2.0f / (e + 1.0f);
}

template <int CTRL>
__device__ __forceinline__ float dppf(float v) {
    return __int_as_float(__builtin_amdgcn_update_dpp(
        0, __float_as_int(v), CTRL, 0xF, 0xF, true));
}
#define DPP_XOR1 0xB1  // quad_perm [1,0,3,2]
#define DPP_XOR2 0x4E  // quad_perm [2,3,0,1]

__device__ __forceinline__ v2f swap2(v2f v) { return __builtin_shufflevector(v, v, 1, 0); }

// ---------------------------------------------------------------------------
// Packed butterflies. State: v2f packs P[j] = (amp(m=2j), amp(m=2j+1)),
// amplitude r = 4m + sub, sub = lane&3.
// ---------------------------------------------------------------------------
template <int MASK>  // pack-to-pack RX (wires 0..2: j bits 2,1,0)
__device__ __forceinline__ void rx_pairs(v2f* zr, v2f* zi, float c, float s) {
#pragma unroll
    for (int j = 0; j < 8; ++j) {
        if (j & MASK) continue;
        int j1 = j | MASK;
        v2f ar = zr[j], ai = zi[j], br = zr[j1], bi = zi[j1];
        zr[j]  = c * ar + s * bi;
        zi[j]  = c * ai - s * br;
        zr[j1] = c * br + s * ai;
        zi[j1] = c * bi - s * ar;
    }
}

template <int CTRL>  // cross-lane RX (wires 4,5: lane bits)
__device__ __forceinline__ void rx_exch2(v2f* zr, v2f* zi, float c, float s) {
#pragma unroll
    for (int j = 0; j < 8; ++j) {
        v2f pr, pi;
        pr.x = dppf<CTRL>(zr[j].x);
        pr.y = dppf<CTRL>(zr[j].y);
        pi.x = dppf<CTRL>(zi[j].x);
        pi.y = dppf<CTRL>(zi[j].y);
        v2f mr = zr[j], mi = zi[j];
        zr[j] = c * mr + s * pi;
        zi[j] = c * mi - s * pr;
    }
}

// wires 1..5 + diagonal of one block (wire 0 handled by caller)
__device__ __forceinline__ void enc_tail(v2f* zr, v2f* zi, const float* rx,
                                         const float* sDblk, int sub) {
    rx_pairs<2>(zr, zi, rx[2], rx[3]);     // wire 1: r bit4 = j bit1
    rx_pairs<1>(zr, zi, rx[4], rx[5]);     // wire 2: r bit3 = j bit0
    {                                       // wire 3: r bit2 = pack half
        float c = rx[6], s = rx[7];
#pragma unroll
        for (int j = 0; j < 8; ++j) {
            v2f orr = zr[j], oi = zi[j];
            zr[j] = c * orr + s * swap2(oi);
            zi[j] = c * oi - s * swap2(orr);
        }
    }
    rx_exch2<DPP_XOR2>(zr, zi, rx[8], rx[9]);    // wire 4: lane bit1
    rx_exch2<DPP_XOR1>(zr, zi, rx[10], rx[11]);  // wire 5: lane bit0
#pragma unroll
    for (int j = 0; j < 8; ++j) {
        float4 d = *(const float4*)&sDblk[(j * 4 + sub) * 4];
        v2f dr = {d.x, d.y}, di = {d.z, d.w};
        v2f orr = zr[j], oi = zi[j];
        zr[j] = dr * orr - di * oi;
        zi[j] = dr * oi + di * orr;
    }
}

// ---------------------------------------------------------------------------
// Fused kernel, ONE group per block (multi-group packaging proven toxic:
// R5/R6/R7 all scratch-spilled). Prep is wave-specialized:
//   wave 0 : decoder butterfly (3-col layout), BARRIER-FREE in-wave lockstep
//   waves 1-2 : stage sW
//   wave 3 : sD diagonal trig
// then 3 barriers total. Main body verbatim R4/R8.
//
// __launch_bounds__(256, 8): VGPR_Count measured 64 == 512/8, so 8 waves/EU
// fits with zero register pressure change; R4/R8 ran at Occupancy 51% with
// (256,4) — this is the single variable changed this round.
// ---------------------------------------------------------------------------
__global__ __launch_bounds__(256, 8) void qae_fused(const float* __restrict__ x,
                                                    const float* __restrict__ Wp,
                                                    const float* __restrict__ bp,
                                                    const float* __restrict__ enc_w,
                                                    const float* __restrict__ dec_w,
                                                    float* __restrict__ out) {
    __shared__ __align__(16) float gt[144];   // 18 gates x 8
    __shared__ __align__(16) float Sr[256];   // [64][4], cols 0..2 live
    __shared__ __align__(16) float Si[256];
    __shared__ float sA[36];
    __shared__ float sRx[36];
    __shared__ __align__(16) float sW[544];
    __shared__ __align__(16) float sB[544];
    __shared__ __align__(16) float sD[256];

    const int t = threadIdx.x;
    const int bl = t >> 2;
    const int sub = t & 3;

    // hoist x load: latency hides under prep
    const size_t b = (size_t)blockIdx.x * 64 + bl;
    const float* xp = x + b * 6;
    float2 x01 = *(const float2*)(xp);
    float2 x23 = *(const float2*)(xp + 2);
    float2 x45 = *(const float2*)(xp + 4);

    if (t < 64) {
        // ================= wave 0: butterfly prep, no barriers =============
        if (t < 18) {
            float tx = dec_w[t * 3 + 0];
            float tz = dec_w[t * 3 + 1];
            float c = cosf(0.5f * tx), s = sinf(0.5f * tx);
            float ch = cosf(0.5f * tz), sh = sinf(0.5f * tz);
            gt[t * 8 + 0] = c * ch;  gt[t * 8 + 1] = -c * sh;
            gt[t * 8 + 2] = -s * sh; gt[t * 8 + 3] = -s * ch;
            gt[t * 8 + 4] = s * sh;  gt[t * 8 + 5] = -s * ch;
            gt[t * 8 + 6] = c * ch;  gt[t * 8 + 7] = c * sh;
            // enc RX coeffs
            float etx = enc_w[t * 3 + 0];
            float ec = cosf(0.5f * etx), es = sinf(0.5f * etx);
            if (t >= 12) {  // block 2 folded into observable
                sRx[2 * t] = ec * ec - es * es;   // cos(tx)
                sRx[2 * t + 1] = 4.0f * ec * es;  // 2*sin(tx)
            } else {
                sRx[2 * t] = ec;
                sRx[2 * t + 1] = es;
            }
        }
        // init Sr/Si[64][4] (col 3 dead-zero)
#pragma unroll
        for (int q = 0; q < 4; ++q) {
            int f = t + 64 * q;
            int r = f >> 2, c = f & 3;
            Sr[f] = (r == c && c < 3) ? 1.0f : 0.0f;
            Si[f] = 0.0f;
        }
        const int cl = t & 3;
        const int pq = t >> 2;   // 0..15
        for (int bb = 0; bb < 3; ++bb) {
            for (int w = 0; w < 6; ++w) {
                int g = bb * 6 + w;
                int p = 5 - w;
                float u00r = gt[g * 8 + 0], u00i = gt[g * 8 + 1];
                float u01r = gt[g * 8 + 2], u01i = gt[g * 8 + 3];
                float u10r = gt[g * 8 + 4], u10i = gt[g * 8 + 5];
                float u11r = gt[g * 8 + 6], u11i = gt[g * 8 + 7];
#pragma unroll
                for (int h = 0; h < 2; ++h) {
                    int pp = pq + 16 * h;
                    int r0 = ((pp >> p) << (p + 1)) | (pp & ((1 << p) - 1));
                    int r1 = r0 | (1 << p);
                    float ar = Sr[r0 * 4 + cl], ai = Si[r0 * 4 + cl];
                    float br = Sr[r1 * 4 + cl], bi = Si[r1 * 4 + cl];
                    Sr[r0 * 4 + cl] = u00r * ar - u00i * ai + u01r * br - u01i * bi;
                    Si[r0 * 4 + cl] = u00r * ai + u00i * ar + u01r * bi + u01i * br;
                    Sr[r1 * 4 + cl] = u10r * ar - u10i * ai + u11r * br - u11i * bi;
                    Si[r1 * 4 + cl] = u10r * ai + u10i * ar + u11r * bi + u11i * br;
                }
            }
            // CZ sign fold (in-wave)
#pragma unroll
            for (int q = 0; q < 4; ++q) {
                int f = t + 64 * q;
                int r = f >> 2;
                if (__popc(r & (r >> 1)) & 1) {
                    Sr[f] = -Sr[f];
                    Si[f] = -Si[f];
                }
            }
        }
    } else if (t < 192) {
        // ================= waves 1-2: stage sW ============================
        // group g = j*4+su holds rows (8j+su, 8j+4+su) interleaved:
        //   phys(g,e) = g*16 + (g>>2)*4 + e; e=2d+half W, 12+half bias, 14 pad
#pragma unroll
        for (int q = 0; q < 4; ++q) {
            int f = (t - 64) + 128 * q;
            int g = f >> 4, e = f & 15;
            int j = g >> 2, su = g & 3;
            float val;
            if (e < 12)      { int row = 8 * j + su + 4 * (e & 1); val = Wp[row * 6 + (e >> 1)]; }
            else if (e < 14) { int row = 8 * j + su + 4 * (e - 12); val = bp[row]; }
            else val = 0.0f;
            sW[g * 16 + j * 4 + e] = val;
        }
    } else {
        // ================= wave 3: sD enc diag trig =======================
        // layout ((bb*8+j)*4+su)*4 = (DrLo,DrHi,DiLo,DiHi)
#pragma unroll
        for (int q = 0; q < 2; ++q) {
            int idx = (t - 192) + 64 * q;
            int bb = idx >> 6, r = idx & 63;
            float phi = 0.0f;
            for (int k = 0; k < 6; ++k) {
                float tz = enc_w[(bb * 6 + k) * 3 + 1];
                phi += ((r >> (5 - k)) & 1) ? 0.5f * tz : -0.5f * tz;
            }
            float sgn = (__popc(r & (r >> 1)) & 1) ? -1.0f : 1.0f;
            int su = r & 3, m = r >> 2, j = m >> 1, hm = m & 1;
            int base = ((bb * 8 + j) * 4 + su) * 4;
            sD[base + hm]     = sgn * cosf(phi);
            sD[base + 2 + hm] = sgn * sinf(phi);
        }
    }
    __syncthreads();

    // folded decoder quadratic forms A' (6 coeffs per output k)
    if (t < 36) {
        int k = t / 6, i = t % 6;
        int d = (i < 3) ? i : ((i == 5) ? 1 : 0);  // i=3->(0,1) i=4->(0,2) i=5->(1,2)
        int e = (i < 3) ? i : ((i == 3) ? 1 : 2);
        float acc = 0.0f;
        for (int r = 0; r < 64; ++r) {
            float term = Sr[r * 4 + d] * Sr[r * 4 + e] + Si[r * 4 + d] * Si[r * 4 + e];
            acc += ((r >> (5 - k)) & 1) ? -term : term;
        }
        if (i >= 3) acc *= 2.0f;  // symmetric off-diagonal folded
        sA[t] = acc;
    }
    __syncthreads();

    // sB: B[row] = W[row,:]·A' (decoder + output matmul collapsed), swizzled
    //   row r at phys r*8 + (r>>4)*4 -> conflict-free b128 reads per sub group
    if (t < 64) {
        float w0 = Wp[t * 6 + 0], w1 = Wp[t * 6 + 1], w2 = Wp[t * 6 + 2];
        float w3 = Wp[t * 6 + 3], w4 = Wp[t * 6 + 4], w5 = Wp[t * 6 + 5];
        int basep = 8 * t + ((t >> 4) << 2);
#pragma unroll
        for (int i = 0; i < 6; ++i) {
            float acc = w0 * sA[0 * 6 + i] + w1 * sA[1 * 6 + i] + w2 * sA[2 * 6 + i]
                      + w3 * sA[3 * 6 + i] + w4 * sA[4 * 6 + i] + w5 * sA[5 * 6 + i];
            sB[basep + i] = acc;
        }
        sB[basep + 6] = bp[t];
        sB[basep + 7] = 0.0f;
    }
    __syncthreads();

    // ================= main compute (verbatim R4/R8) =======================
    float xv[6] = {x01.x, x01.y, x23.x, x23.y, x45.x, x45.y};

    // h = tanh(xW^T+b): pack j holds rows (8j+sub, 8j+4+sub). zi starts 0.
    v2f zr[8], zi[8];
    v2f S2 = {0.0f, 0.0f};
#pragma unroll
    for (int j = 0; j < 8; ++j) {
        const float* wb = &sW[(j * 4 + sub) * 16 + j * 4];
        float4 c0 = *(const float4*)wb;
        float4 c1 = *(const float4*)(wb + 4);
        float4 c2 = *(const float4*)(wb + 8);
        float4 c3 = *(const float4*)(wb + 12);
        v2f a = {c3.x, c3.y};
        a += xv[0] * (v2f){c0.x, c0.y};
        a += xv[1] * (v2f){c0.z, c0.w};
        a += xv[2] * (v2f){c1.x, c1.y};
        a += xv[3] * (v2f){c1.z, c1.w};
        a += xv[4] * (v2f){c2.x, c2.y};
        a += xv[5] * (v2f){c2.z, c2.w};
        v2f th = {fast_tanh(a.x), fast_tanh(a.y)};
        zr[j] = th;
        S2 += th * th;
    }
    float S = S2.x + S2.y;
    S += dppf<DPP_XOR1>(S);
    S += dppf<DPP_XOR2>(S);
    float invS = __builtin_amdgcn_rcpf(S);

    // ---- block 0: wire 0 specialized for real input (zi==0) ----
    {
        const float* rx = sRx;
        float c = rx[0], s = rx[1];
#pragma unroll
        for (int j = 0; j < 4; ++j) {
            v2f a = zr[j], b2 = zr[j + 4];
            zr[j]     = c * a;
            zi[j]     = -s * b2;
            zr[j + 4] = c * b2;
            zi[j + 4] = -s * a;
        }
        enc_tail(zr, zi, rx, sD, sub);
    }
    // ---- block 1: generic ----
    {
        const float* rx = sRx + 12;
        rx_pairs<4>(zr, zi, rx[0], rx[1]);
        enc_tail(zr, zi, rx, sD + 128, sub);
    }

    // latent via folded block-2 observable:
    //   latent_k = (cos(tx_k)*<Z_k> + sin(tx_k)*<Y_k>)/S
    v2f L0 = {0, 0}, L1 = {0, 0}, L2 = {0, 0};
#pragma unroll
    for (int j = 0; j < 8; ++j) {
        v2f p = zr[j] * zr[j] + zi[j] * zi[j];
        L0 += (j & 4) ? -p : p;
        L1 += (j & 2) ? -p : p;
        L2 += (j & 1) ? -p : p;
    }
    v2f Y0 = {0, 0}, Y1 = {0, 0}, Y2 = {0, 0};
#pragma unroll
    for (int j = 0; j < 4; ++j)
        Y0 += zr[j] * zi[j | 4] - zi[j] * zr[j | 4];
#pragma unroll
    for (int j0 = 0; j0 < 8; j0 += 4)
#pragma unroll
        for (int j = j0; j < j0 + 2; ++j)
            Y1 += zr[j] * zi[j | 2] - zi[j] * zr[j | 2];
#pragma unroll
    for (int j = 0; j < 8; j += 2)
        Y2 += zr[j] * zi[j | 1] - zi[j] * zr[j | 1];

    // combine with block-2 coeffs BEFORE cross-lane reduce: 6 DPP not 12
    const float* p2 = sRx + 24;
    float t0 = p2[0] * (L0.x + L0.y) + p2[1] * (Y0.x + Y0.y);
    float t1 = p2[2] * (L1.x + L1.y) + p2[3] * (Y1.x + Y1.y);
    float t2 = p2[4] * (L2.x + L2.y) + p2[5] * (Y2.x + Y2.y);
    t0 += dppf<DPP_XOR1>(t0); t0 += dppf<DPP_XOR2>(t0);
    t1 += dppf<DPP_XOR1>(t1); t1 += dppf<DPP_XOR2>(t1);
    t2 += dppf<DPP_XOR1>(t2); t2 += dppf<DPP_XOR2>(t2);
    float l0 = t0 * invS, l1 = t1 * invS, l2 = t2 * invS;

    // latent out (direct, no LDS round-trip / no barrier)
    if (sub == 0) {
        size_t lo = (size_t)BATCH * 64 + b * 3;
        out[lo]     = l0;
        out[lo + 1] = l1;
        out[lo + 2] = l2;
    }

    // q-hat = q * inv(l^T l); pre_row = B[row]·q-hat + bias_row
    float q0 = l0 * l0, q1 = l1 * l1, q2 = l2 * l2;
    float invr2 = __builtin_amdgcn_rcpf(q0 + q1 + q2);
    float qh0 = q0 * invr2, qh1 = q1 * invr2, qh2 = q2 * invr2;
    float qh3 = (l0 * l1) * invr2, qh4 = (l0 * l2) * invr2, qh5 = (l1 * l2) * invr2;

    // reconstructed = tanh(B q-hat + b); thread covers rows 16*sub..16*sub+15
    const float* bB = &sB[132 * sub];   // 132 = 16*8 + 4 (swizzled row base)
    const size_t ob = b * 64 + 16 * sub;
#pragma unroll
    for (int ch = 0; ch < 4; ++ch) {
        float v4[4];
#pragma unroll
        for (int r = 0; r < 4; ++r) {
            int qq = ch * 4 + r;
            float4 u0 = *(const float4*)&bB[8 * qq];
            float4 u1 = *(const float4*)&bB[8 * qq + 4];  // B4,B5,bias,pad
            float acc = u1.z
                      + qh0 * u0.x + qh1 * u0.y + qh2 * u0.z + qh3 * u0.w
                      + qh4 * u1.x + qh5 * u1.y;
            v4[r] = fast_tanh(acc);
        }
        float4 o = {v4[0], v4[1], v4[2], v4[3]};
        *(float4*)&out[ob + ch * 4] = o;
    }
}

extern "C" void kernel_launch(void* const* d_in, const int* in_sizes, int n_in,
                              void* d_out, int out_size, void* d_ws, size_t ws_size,
                              hipStream_t stream) {
    const float* x   = (const float*)d_in[0];
    const float* Wp  = (const float*)d_in[1];
    const float* bpv = (const float*)d_in[2];
    const float* enc = (const float*)d_in[3];
    const float* dec = (const float*)d_in[4];
    float* out = (float*)d_out;

    qae_fused<<<(BATCH * 4) / 256, 256, 0, stream>>>(x, Wp, bpv, enc, dec, out);
}